// Round 4
// baseline (560.209 us; speedup 1.0000x reference)
//
#include <hip/hip_runtime.h>
#include <stdint.h>

#define HH    256
#define DD    96
#define NH    6
#define WSZ   8

typedef __bf16 bf16_t;
typedef bf16_t bf16x8 __attribute__((ext_vector_type(8)));
typedef float  f32x4  __attribute__((ext_vector_type(4)));

union U4 { bf16x8 v; uint32_t u[4]; };
union U2 { bf16_t h[2]; uint32_t u; };

static __device__ __forceinline__ uint32_t pack2(float a, float b) {
    U2 x; x.h[0] = (bf16_t)a; x.h[1] = (bf16_t)b; return x.u;
}

// ---- workspace layout (bytes) ----
#define OFF_WQ_HI 0        // 18*3*64*8 bf16 = 55296 B
#define OFF_WQ_LO 55296
#define OFF_WO_HI 110592   // 6*3*64*8 bf16 = 18432 B
#define OFF_WO_LO 129024
#define OFF_RPE   147456   // 6*64*64 f32 = 98304 B, layout [h][q][k]
// total 245760 B

// ---- LDS overlay arena (bytes): 38400 total ----
// phase 0/1: xs_hi @0 (12288) | xs_lo @12288 (12288)
// phase 2  : qs @0 (12288) | ks @12288 (12288) | vt @24576 (13824)
// phase 3  : o_hi @0 (12288) | o_lo @12288 (12288)
#define LDS_BYTES 38400

__global__ __launch_bounds__(256)
void prep_kernel(const float* __restrict__ wqkv, const float* __restrict__ wout,
                 const float* __restrict__ rpe, char* __restrict__ ws)
{
    bf16_t* wq_hi = (bf16_t*)(ws + OFF_WQ_HI);
    bf16_t* wq_lo = (bf16_t*)(ws + OFF_WQ_LO);
    bf16_t* wo_hi = (bf16_t*)(ws + OFF_WO_HI);
    bf16_t* wo_lo = (bf16_t*)(ws + OFF_WO_LO);
    float*  rpe_b = (float*)(ws + OFF_RPE);

    int idx = blockIdx.x * 256 + threadIdx.x;
    // w_qkv fragments: [nt<18][ks<3][lane][8]
    if (idx < 27648) {
        int j = idx & 7, lane = (idx >> 3) & 63, rest = idx >> 9;
        int ks = rest % 3, nt = rest / 3;
        int k = ks * 32 + ((lane >> 4) << 3) + j;
        int n = nt * 16 + (lane & 15);
        float v = wqkv[k * 288 + n];
        bf16_t h = (bf16_t)v;
        wq_hi[idx] = h;
        wq_lo[idx] = (bf16_t)(v - (float)h);
    }
    // w_out fragments: [nt<6][ks<3][lane][8]
    if (idx < 9216) {
        int j = idx & 7, lane = (idx >> 3) & 63, rest = idx >> 9;
        int ks = rest % 3, nt = rest / 3;
        int k = ks * 32 + ((lane >> 4) << 3) + j;
        int n = nt * 16 + (lane & 15);
        float v = wout[k * 96 + n];
        bf16_t h = (bf16_t)v;
        wo_hi[idx] = h;
        wo_lo[idx] = (bf16_t)(v - (float)h);
    }
    // expanded rpe bias: [h][q][k] (k contiguous -> float4 loads in main kernel)
    if (idx < 24576) {
        int h = idx >> 12, r = idx & 4095, q = r >> 6, k = r & 63;
        int qr = q >> 3, qc = q & 7, kr = k >> 3, kc = k & 7;
        rpe_b[idx] = rpe[((qr - kr + 7) * 15 + (qc - kc + 7)) * NH + h];
    }
}

__global__ __launch_bounds__(384, 6)
void swin_mfma(const float* __restrict__ x,
               const float* __restrict__ b_qkv,
               const float* __restrict__ b_out,
               const char*  __restrict__ ws,
               float* __restrict__ out)
{
    extern __shared__ char smem[];
    bf16_t* xs_hi = (bf16_t*)(smem);            // phase 0/1
    bf16_t* xs_lo = (bf16_t*)(smem + 12288);
    bf16_t* qs    = (bf16_t*)(smem);            // phase 2 (overlay)
    bf16_t* ks_l  = (bf16_t*)(smem + 12288);
    bf16_t* vt    = (bf16_t*)(smem + 24576);
    bf16_t* o_hi  = (bf16_t*)(smem);            // phase 3 (overlay)
    bf16_t* o_lo  = (bf16_t*)(smem + 12288);

    const bf16_t* wq_hi = (const bf16_t*)(ws + OFF_WQ_HI);
    const bf16_t* wq_lo = (const bf16_t*)(ws + OFF_WQ_LO);
    const bf16_t* wo_hi = (const bf16_t*)(ws + OFF_WO_HI);
    const bf16_t* wo_lo = (const bf16_t*)(ws + OFF_WO_LO);
    const float*  rpe_b = (const float*)(ws + OFF_RPE);

    const int blk = blockIdx.x;
    const int b   = blk >> 10;
    const int wi  = (blk >> 5) & 31;
    const int wj  = blk & 31;

    const int tid  = threadIdx.x;
    const int lane = tid & 63;
    const int w    = tid >> 6;      // wave = head
    const int g    = lane >> 4;     // lane group 0..3
    const int c    = lane & 15;

    const f32x4 zf = {0.f, 0.f, 0.f, 0.f};

    // ---- Phase 0: stage x -> xs_hi/xs_lo (shifted gather) ----
    #pragma unroll
    for (int it = 0; it < 4; ++it) {
        int f4  = tid + it * 384;          // float4 index over [64][24]
        int row = f4 / 24, c4 = f4 - row * 24;
        int r = row >> 3, cl = row & 7;
        int gh = (wi * WSZ + r + 4) & 255;
        int gw = (wj * WSZ + cl + 4) & 255;
        const float4 v = *(const float4*)(x + (((size_t)b * HH + gh) * HH + gw) * DD + c4 * 4);
        float f0 = v.x, f1 = v.y, f2 = v.z, f3 = v.w;
        bf16_t h0 = (bf16_t)f0, h1 = (bf16_t)f1, h2 = (bf16_t)f2, h3 = (bf16_t)f3;
        uint2 hv, lv;
        hv.x = pack2(f0, f1); hv.y = pack2(f2, f3);
        lv.x = pack2(f0 - (float)h0, f1 - (float)h1);
        lv.y = pack2(f2 - (float)h2, f3 - (float)h3);
        *(uint2*)&xs_hi[row * 96 + c4 * 4] = hv;
        *(uint2*)&xs_lo[row * 96 + c4 * 4] = lv;
    }
    __syncthreads();

    // ---- Phase 1: QKV projection (split-bf16, 3-term). Wave w owns n-tiles {w, 6+w, 12+w} ----
    f32x4 acc[3][4];
    #pragma unroll
    for (int t = 0; t < 3; ++t) {
        float bias = b_qkv[t * 96 + w * 16 + c];
        #pragma unroll
        for (int mt = 0; mt < 4; ++mt) acc[t][mt] = (f32x4){bias, bias, bias, bias};
    }
    #pragma unroll
    for (int ks = 0; ks < 3; ++ks) {
        bf16x8 ah[4], al[4];
        #pragma unroll
        for (int mt = 0; mt < 4; ++mt) {
            ah[mt] = *(const bf16x8*)&xs_hi[(mt * 16 + c) * 96 + ks * 32 + g * 8];
            al[mt] = *(const bf16x8*)&xs_lo[(mt * 16 + c) * 96 + ks * 32 + g * 8];
        }
        #pragma unroll
        for (int t = 0; t < 3; ++t) {
            int nt = t * 6 + w;
            const bf16x8 bh = *(const bf16x8*)&wq_hi[((nt * 3 + ks) * 64 + lane) * 8];
            const bf16x8 bl = *(const bf16x8*)&wq_lo[((nt * 3 + ks) * 64 + lane) * 8];
            #pragma unroll
            for (int mt = 0; mt < 4; ++mt) {
                acc[t][mt] = __builtin_amdgcn_mfma_f32_16x16x32_bf16(ah[mt], bh, acc[t][mt], 0, 0, 0);
                acc[t][mt] = __builtin_amdgcn_mfma_f32_16x16x32_bf16(ah[mt], bl, acc[t][mt], 0, 0, 0);
                acc[t][mt] = __builtin_amdgcn_mfma_f32_16x16x32_bf16(al[mt], bh, acc[t][mt], 0, 0, 0);
            }
        }
    }
    __syncthreads();   // all proj reads of xs done -> overlay becomes legal

    // write Q (x0.25), K, V^T for head w into the overlay arena
    #pragma unroll
    for (int mt = 0; mt < 4; ++mt) {
        #pragma unroll
        for (int i = 0; i < 4; ++i) {
            int row = mt * 16 + g * 4 + i;
            qs[w * 1024 + row * 16 + c]   = (bf16_t)(acc[0][mt][i] * 0.25f);
            ks_l[w * 1024 + row * 16 + c] = (bf16_t)acc[1][mt][i];
            vt[w * 1152 + c * 72 + row]   = (bf16_t)acc[2][mt][i];
        }
    }
    __syncthreads();

    // ---- Phase 2: attention for head w (S^T = K @ Q^T, K-dim 16 zero-padded to 32) ----
    U4 z4; z4.u[0] = z4.u[1] = z4.u[2] = z4.u[3] = 0;
    bf16x8 ak[4], bq[4];
    #pragma unroll
    for (int kt = 0; kt < 4; ++kt) {
        U4 t = z4;
        if (g < 2) t.v = *(const bf16x8*)&ks_l[w * 1024 + (kt * 16 + c) * 16 + g * 8];
        ak[kt] = t.v;
    }
    #pragma unroll
    for (int nt = 0; nt < 4; ++nt) {
        U4 t = z4;
        if (g < 2) t.v = *(const bf16x8*)&qs[w * 1024 + (nt * 16 + c) * 16 + g * 8];
        bq[nt] = t.v;
    }
    f32x4 st[4][4];
    #pragma unroll
    for (int kt = 0; kt < 4; ++kt)
        #pragma unroll
        for (int nt = 0; nt < 4; ++nt)
            st[kt][nt] = __builtin_amdgcn_mfma_f32_16x16x32_bf16(ak[kt], bq[nt], zf, 0, 0, 0);

    // rpe + mask + softmax (per lane: 4 q's x 16 k's; row-reduce over 4 lanes)
    const float* rpe_w = rpe_b + w * 4096;
    const int e_wi = (wi == 31), e_wj = (wj == 31);
    const bool edge = e_wi || e_wj;
    int rk[4][4];
    #pragma unroll
    for (int kt = 0; kt < 4; ++kt)
        #pragma unroll
        for (int i = 0; i < 4; ++i) {
            int k = kt * 16 + g * 4 + i;
            int kr = k >> 3, kc = k & 7;
            rk[kt][i] = (e_wi ? (kr >= 4 ? 2 : 1) : 0) * 3 + (e_wj ? (kc >= 4 ? 2 : 1) : 0);
        }

    uint32_t pk[4][4][2];
    #pragma unroll
    for (int nt = 0; nt < 4; ++nt) {
        int q = nt * 16 + c, qr = q >> 3, qc = q & 7;
        int rq = (e_wi ? (qr >= 4 ? 2 : 1) : 0) * 3 + (e_wj ? (qc >= 4 ? 2 : 1) : 0);
        float sv[16];
        float m = -3.0e38f;
        #pragma unroll
        for (int kt = 0; kt < 4; ++kt) {
            const float4 rv = *(const float4*)&rpe_w[q * 64 + kt * 16 + g * 4];
            #pragma unroll
            for (int i = 0; i < 4; ++i) {
                float s = st[kt][nt][i] + ((const float*)&rv)[i];
                if (edge && (rk[kt][i] != rq)) s = -1e9f;
                sv[kt * 4 + i] = s;
                m = fmaxf(m, s);
            }
        }
        m = fmaxf(m, __shfl_xor(m, 16));
        m = fmaxf(m, __shfl_xor(m, 32));
        float sum = 0.f;
        #pragma unroll
        for (int e = 0; e < 16; ++e) { sv[e] = __expf(sv[e] - m); sum += sv[e]; }
        sum += __shfl_xor(sum, 16);
        sum += __shfl_xor(sum, 32);
        float rinv = 1.0f / sum;
        #pragma unroll
        for (int kt = 0; kt < 4; ++kt) {
            pk[nt][kt][0] = pack2(sv[kt * 4 + 0] * rinv, sv[kt * 4 + 1] * rinv);
            pk[nt][kt][1] = pack2(sv[kt * 4 + 2] * rinv, sv[kt * 4 + 3] * rinv);
        }
    }

    // PV: O = P @ V, A-frags assembled via shuffles from register P
    f32x4 oacc[4];
    #pragma unroll
    for (int mt = 0; mt < 4; ++mt) oacc[mt] = zf;
    #pragma unroll
    for (int ks = 0; ks < 2; ++ks) {
        const bf16x8 bv = *(const bf16x8*)&vt[w * 1152 + c * 72 + ks * 32 + g * 8];
        #pragma unroll
        for (int mt = 0; mt < 4; ++mt) {
            U4 af;
            #pragma unroll
            for (int jj = 0; jj < 4; ++jj) {
                int srcg = ((g & 1) << 1) + (jj >> 1);
                int src  = (srcg << 4) + c;
                uint32_t v0 = (uint32_t)__shfl((int)pk[mt][ks * 2 + 0][jj & 1], src);
                uint32_t v1 = (uint32_t)__shfl((int)pk[mt][ks * 2 + 1][jj & 1], src);
                af.u[jj] = (g >= 2) ? v1 : v0;
            }
            oacc[mt] = __builtin_amdgcn_mfma_f32_16x16x32_bf16(af.v, bv, oacc[mt], 0, 0, 0);
        }
    }
    __syncthreads();   // all reads of qs/ks/vt done -> o overlay becomes legal

    // write attention output (split) into overlay
    #pragma unroll
    for (int mt = 0; mt < 4; ++mt)
        #pragma unroll
        for (int i = 0; i < 4; ++i) {
            int row = mt * 16 + g * 4 + i;
            float f = oacc[mt][i];
            bf16_t h = (bf16_t)f;
            o_hi[row * 96 + w * 16 + c] = h;
            o_lo[row * 96 + w * 16 + c] = (bf16_t)(f - (float)h);
        }
    __syncthreads();

    // ---- Phase 3: out-projection (split-bf16, 3-term). Wave w -> cols [w*16, w*16+16) ----
    f32x4 acc3[4];
    {
        float bo = b_out[w * 16 + c];
        #pragma unroll
        for (int mt = 0; mt < 4; ++mt) acc3[mt] = (f32x4){bo, bo, bo, bo};
    }
    #pragma unroll
    for (int ks = 0; ks < 3; ++ks) {
        bf16x8 ah[4], al[4];
        #pragma unroll
        for (int mt = 0; mt < 4; ++mt) {
            ah[mt] = *(const bf16x8*)&o_hi[(mt * 16 + c) * 96 + ks * 32 + g * 8];
            al[mt] = *(const bf16x8*)&o_lo[(mt * 16 + c) * 96 + ks * 32 + g * 8];
        }
        const bf16x8 bh = *(const bf16x8*)&wo_hi[((w * 3 + ks) * 64 + lane) * 8];
        const bf16x8 bl = *(const bf16x8*)&wo_lo[((w * 3 + ks) * 64 + lane) * 8];
        #pragma unroll
        for (int mt = 0; mt < 4; ++mt) {
            acc3[mt] = __builtin_amdgcn_mfma_f32_16x16x32_bf16(ah[mt], bh, acc3[mt], 0, 0, 0);
            acc3[mt] = __builtin_amdgcn_mfma_f32_16x16x32_bf16(ah[mt], bl, acc3[mt], 0, 0, 0);
            acc3[mt] = __builtin_amdgcn_mfma_f32_16x16x32_bf16(al[mt], bh, acc3[mt], 0, 0, 0);
        }
    }
    // store (shifted scatter)
    #pragma unroll
    for (int mt = 0; mt < 4; ++mt)
        #pragma unroll
        for (int i = 0; i < 4; ++i) {
            int row = mt * 16 + g * 4 + i;
            int r = row >> 3, cl = row & 7;
            int gh = (wi * WSZ + r + 4) & 255;
            int gw = (wj * WSZ + cl + 4) & 255;
            out[(((size_t)b * HH + gh) * HH + gw) * DD + w * 16 + c] = acc3[mt][i];
        }
}

extern "C" void kernel_launch(void* const* d_in, const int* in_sizes, int n_in,
                              void* d_out, int out_size, void* d_ws, size_t ws_size,
                              hipStream_t stream) {
    const float* x    = (const float*)d_in[0];
    const float* wqkv = (const float*)d_in[1];
    const float* bqkv = (const float*)d_in[2];
    const float* wout = (const float*)d_in[3];
    const float* bout = (const float*)d_in[4];
    const float* rpe  = (const float*)d_in[5];
    float* out = (float*)d_out;
    char* ws = (char*)d_ws;

    const int B = in_sizes[0] / (HH * HH * DD);

    hipLaunchKernelGGL(prep_kernel, dim3(108), dim3(256), 0, stream, wqkv, wout, rpe, ws);
    hipLaunchKernelGGL(swin_mfma, dim3(B * 1024), dim3(384), LDS_BYTES, stream,
                       x, bqkv, bout, (const char*)ws, out);
}

// Round 5
// 302.773 us; speedup vs baseline: 1.8503x; 1.8503x over previous
//
#include <hip/hip_runtime.h>
#include <stdint.h>

#define HH    256
#define DD    96
#define NH    6
#define WSZ   8

typedef __bf16 bf16_t;
typedef bf16_t bf16x8 __attribute__((ext_vector_type(8)));
typedef float  f32x4  __attribute__((ext_vector_type(4)));

union U4 { bf16x8 v; uint32_t u[4]; };
union U2 { bf16_t h[2]; uint32_t u; };

static __device__ __forceinline__ uint32_t pack2(float a, float b) {
    U2 x; x.h[0] = (bf16_t)a; x.h[1] = (bf16_t)b; return x.u;
}

// ---- workspace layout (bytes) ----
#define OFF_WQ_HI 0        // 18*3*64*8 bf16 = 55296 B
#define OFF_WQ_LO 55296
#define OFF_WO_HI 110592   // 6*3*64*8 bf16 = 18432 B
#define OFF_WO_LO 129024
#define OFF_RPE   147456   // 6*64*64 f32 = 98304 B, layout [h][q][k]
// total 245760 B

// ---- LDS overlay arena (bytes): 38400 total -> 4 blocks/CU ----
// phase 0/1: xs_hi @0 (12288) | xs_lo @12288 (12288)
// phase 2  : qs @0 (12288) | ks @12288 (12288) | vt @24576 (13824)
// phase 3  : o_hi @0 (12288) | o_lo @12288 (12288)
#define LDS_BYTES 38400

__global__ __launch_bounds__(256)
void prep_kernel(const float* __restrict__ wqkv, const float* __restrict__ wout,
                 const float* __restrict__ rpe, char* __restrict__ ws)
{
    bf16_t* wq_hi = (bf16_t*)(ws + OFF_WQ_HI);
    bf16_t* wq_lo = (bf16_t*)(ws + OFF_WQ_LO);
    bf16_t* wo_hi = (bf16_t*)(ws + OFF_WO_HI);
    bf16_t* wo_lo = (bf16_t*)(ws + OFF_WO_LO);
    float*  rpe_b = (float*)(ws + OFF_RPE);

    int idx = blockIdx.x * 256 + threadIdx.x;
    // w_qkv fragments: [nt<18][ks<3][lane][8]
    if (idx < 27648) {
        int j = idx & 7, lane = (idx >> 3) & 63, rest = idx >> 9;
        int ks = rest % 3, nt = rest / 3;
        int k = ks * 32 + ((lane >> 4) << 3) + j;
        int n = nt * 16 + (lane & 15);
        float v = wqkv[k * 288 + n];
        bf16_t h = (bf16_t)v;
        wq_hi[idx] = h;
        wq_lo[idx] = (bf16_t)(v - (float)h);
    }
    // w_out fragments: [nt<6][ks<3][lane][8]
    if (idx < 9216) {
        int j = idx & 7, lane = (idx >> 3) & 63, rest = idx >> 9;
        int ks = rest % 3, nt = rest / 3;
        int k = ks * 32 + ((lane >> 4) << 3) + j;
        int n = nt * 16 + (lane & 15);
        float v = wout[k * 96 + n];
        bf16_t h = (bf16_t)v;
        wo_hi[idx] = h;
        wo_lo[idx] = (bf16_t)(v - (float)h);
    }
    // expanded rpe bias: [h][q][k] (k contiguous -> float4 loads in main kernel)
    if (idx < 24576) {
        int h = idx >> 12, r = idx & 4095, q = r >> 6, k = r & 63;
        int qr = q >> 3, qc = q & 7, kr = k >> 3, kc = k & 7;
        rpe_b[idx] = rpe[((qr - kr + 7) * 15 + (qc - kc + 7)) * NH + h];
    }
}

__global__ __launch_bounds__(384, 4)
void swin_mfma(const float* __restrict__ x,
               const float* __restrict__ b_qkv,
               const float* __restrict__ b_out,
               const char*  __restrict__ ws,
               float* __restrict__ out)
{
    extern __shared__ char smem[];
    bf16_t* xs_hi = (bf16_t*)(smem);            // phase 0/1
    bf16_t* xs_lo = (bf16_t*)(smem + 12288);
    bf16_t* qs    = (bf16_t*)(smem);            // phase 2 (overlay)
    bf16_t* ks_l  = (bf16_t*)(smem + 12288);
    bf16_t* vt    = (bf16_t*)(smem + 24576);
    bf16_t* o_hi  = (bf16_t*)(smem);            // phase 3 (overlay)
    bf16_t* o_lo  = (bf16_t*)(smem + 12288);

    const bf16_t* wq_hi = (const bf16_t*)(ws + OFF_WQ_HI);
    const bf16_t* wq_lo = (const bf16_t*)(ws + OFF_WQ_LO);
    const bf16_t* wo_hi = (const bf16_t*)(ws + OFF_WO_HI);
    const bf16_t* wo_lo = (const bf16_t*)(ws + OFF_WO_LO);
    const float*  rpe_b = (const float*)(ws + OFF_RPE);

    const int blk = blockIdx.x;
    const int b   = blk >> 10;
    const int wi  = (blk >> 5) & 31;
    const int wj  = blk & 31;

    const int tid  = threadIdx.x;
    const int lane = tid & 63;
    const int w    = tid >> 6;      // wave = head
    const int g    = lane >> 4;     // lane group 0..3
    const int c    = lane & 15;

    const f32x4 zf = {0.f, 0.f, 0.f, 0.f};

    // ---- Phase 0: stage x -> xs_hi/xs_lo (shifted gather) ----
    #pragma unroll
    for (int it = 0; it < 4; ++it) {
        int f4  = tid + it * 384;          // float4 index over [64][24]
        int row = f4 / 24, c4 = f4 - row * 24;
        int r = row >> 3, cl = row & 7;
        int gh = (wi * WSZ + r + 4) & 255;
        int gw = (wj * WSZ + cl + 4) & 255;
        const float4 v = *(const float4*)(x + (((size_t)b * HH + gh) * HH + gw) * DD + c4 * 4);
        float f0 = v.x, f1 = v.y, f2 = v.z, f3 = v.w;
        bf16_t h0 = (bf16_t)f0, h1 = (bf16_t)f1, h2 = (bf16_t)f2, h3 = (bf16_t)f3;
        uint2 hv, lv;
        hv.x = pack2(f0, f1); hv.y = pack2(f2, f3);
        lv.x = pack2(f0 - (float)h0, f1 - (float)h1);
        lv.y = pack2(f2 - (float)h2, f3 - (float)h3);
        *(uint2*)&xs_hi[row * 96 + c4 * 4] = hv;
        *(uint2*)&xs_lo[row * 96 + c4 * 4] = lv;
    }
    __syncthreads();

    // ---- Phase 1: QKV projection (split-bf16, 3-term). Wave w owns n-tiles {w, 6+w, 12+w} ----
    f32x4 acc[3][4];
    #pragma unroll
    for (int t = 0; t < 3; ++t) {
        float bias = b_qkv[t * 96 + w * 16 + c];
        #pragma unroll
        for (int mt = 0; mt < 4; ++mt) acc[t][mt] = (f32x4){bias, bias, bias, bias};
    }
    #pragma unroll
    for (int ks = 0; ks < 3; ++ks) {
        bf16x8 ah[4], al[4];
        #pragma unroll
        for (int mt = 0; mt < 4; ++mt) {
            ah[mt] = *(const bf16x8*)&xs_hi[(mt * 16 + c) * 96 + ks * 32 + g * 8];
            al[mt] = *(const bf16x8*)&xs_lo[(mt * 16 + c) * 96 + ks * 32 + g * 8];
        }
        #pragma unroll
        for (int t = 0; t < 3; ++t) {
            int nt = t * 6 + w;
            const bf16x8 bh = *(const bf16x8*)&wq_hi[((nt * 3 + ks) * 64 + lane) * 8];
            const bf16x8 bl = *(const bf16x8*)&wq_lo[((nt * 3 + ks) * 64 + lane) * 8];
            #pragma unroll
            for (int mt = 0; mt < 4; ++mt) {
                acc[t][mt] = __builtin_amdgcn_mfma_f32_16x16x32_bf16(ah[mt], bh, acc[t][mt], 0, 0, 0);
                acc[t][mt] = __builtin_amdgcn_mfma_f32_16x16x32_bf16(ah[mt], bl, acc[t][mt], 0, 0, 0);
                acc[t][mt] = __builtin_amdgcn_mfma_f32_16x16x32_bf16(al[mt], bh, acc[t][mt], 0, 0, 0);
            }
        }
    }
    __syncthreads();   // all proj reads of xs done -> overlay becomes legal

    // write Q (x0.25), K, V^T for head w into the overlay arena
    #pragma unroll
    for (int mt = 0; mt < 4; ++mt) {
        #pragma unroll
        for (int i = 0; i < 4; ++i) {
            int row = mt * 16 + g * 4 + i;
            qs[w * 1024 + row * 16 + c]   = (bf16_t)(acc[0][mt][i] * 0.25f);
            ks_l[w * 1024 + row * 16 + c] = (bf16_t)acc[1][mt][i];
            vt[w * 1152 + c * 72 + row]   = (bf16_t)acc[2][mt][i];
        }
    }
    __syncthreads();

    // ---- Phase 2: attention for head w (S^T = K @ Q^T, K-dim 16 zero-padded to 32) ----
    U4 z4; z4.u[0] = z4.u[1] = z4.u[2] = z4.u[3] = 0;
    bf16x8 ak[4], bq[4];
    #pragma unroll
    for (int kt = 0; kt < 4; ++kt) {
        U4 t = z4;
        if (g < 2) t.v = *(const bf16x8*)&ks_l[w * 1024 + (kt * 16 + c) * 16 + g * 8];
        ak[kt] = t.v;
    }
    #pragma unroll
    for (int nt = 0; nt < 4; ++nt) {
        U4 t = z4;
        if (g < 2) t.v = *(const bf16x8*)&qs[w * 1024 + (nt * 16 + c) * 16 + g * 8];
        bq[nt] = t.v;
    }
    f32x4 st[4][4];
    #pragma unroll
    for (int kt = 0; kt < 4; ++kt)
        #pragma unroll
        for (int nt = 0; nt < 4; ++nt)
            st[kt][nt] = __builtin_amdgcn_mfma_f32_16x16x32_bf16(ak[kt], bq[nt], zf, 0, 0, 0);

    // rpe + mask + softmax (per lane: 4 q's x 16 k's; row-reduce over 4 lanes)
    const float* rpe_w = rpe_b + w * 4096;
    const int e_wi = (wi == 31), e_wj = (wj == 31);
    const bool edge = e_wi || e_wj;
    int rk[4][4];
    #pragma unroll
    for (int kt = 0; kt < 4; ++kt)
        #pragma unroll
        for (int i = 0; i < 4; ++i) {
            int k = kt * 16 + g * 4 + i;
            int kr = k >> 3, kc = k & 7;
            rk[kt][i] = (e_wi ? (kr >= 4 ? 2 : 1) : 0) * 3 + (e_wj ? (kc >= 4 ? 2 : 1) : 0);
        }

    uint32_t pk[4][4][2];
    #pragma unroll
    for (int nt = 0; nt < 4; ++nt) {
        int q = nt * 16 + c, qr = q >> 3, qc = q & 7;
        int rq = (e_wi ? (qr >= 4 ? 2 : 1) : 0) * 3 + (e_wj ? (qc >= 4 ? 2 : 1) : 0);
        float sv[16];
        float m = -3.0e38f;
        #pragma unroll
        for (int kt = 0; kt < 4; ++kt) {
            const float4 rv = *(const float4*)&rpe_w[q * 64 + kt * 16 + g * 4];
            #pragma unroll
            for (int i = 0; i < 4; ++i) {
                float s = st[kt][nt][i] + ((const float*)&rv)[i];
                if (edge && (rk[kt][i] != rq)) s = -1e9f;
                sv[kt * 4 + i] = s;
                m = fmaxf(m, s);
            }
        }
        m = fmaxf(m, __shfl_xor(m, 16));
        m = fmaxf(m, __shfl_xor(m, 32));
        float sum = 0.f;
        #pragma unroll
        for (int e = 0; e < 16; ++e) { sv[e] = __expf(sv[e] - m); sum += sv[e]; }
        sum += __shfl_xor(sum, 16);
        sum += __shfl_xor(sum, 32);
        float rinv = 1.0f / sum;
        #pragma unroll
        for (int kt = 0; kt < 4; ++kt) {
            pk[nt][kt][0] = pack2(sv[kt * 4 + 0] * rinv, sv[kt * 4 + 1] * rinv);
            pk[nt][kt][1] = pack2(sv[kt * 4 + 2] * rinv, sv[kt * 4 + 3] * rinv);
        }
    }

    // PV: O = P @ V, A-frags assembled via shuffles from register P
    f32x4 oacc[4];
    #pragma unroll
    for (int mt = 0; mt < 4; ++mt) oacc[mt] = zf;
    #pragma unroll
    for (int ks = 0; ks < 2; ++ks) {
        const bf16x8 bv = *(const bf16x8*)&vt[w * 1152 + c * 72 + ks * 32 + g * 8];
        #pragma unroll
        for (int mt = 0; mt < 4; ++mt) {
            U4 af;
            #pragma unroll
            for (int jj = 0; jj < 4; ++jj) {
                int srcg = ((g & 1) << 1) + (jj >> 1);
                int src  = (srcg << 4) + c;
                uint32_t v0 = (uint32_t)__shfl((int)pk[mt][ks * 2 + 0][jj & 1], src);
                uint32_t v1 = (uint32_t)__shfl((int)pk[mt][ks * 2 + 1][jj & 1], src);
                af.u[jj] = (g >= 2) ? v1 : v0;
            }
            oacc[mt] = __builtin_amdgcn_mfma_f32_16x16x32_bf16(af.v, bv, oacc[mt], 0, 0, 0);
        }
    }
    __syncthreads();   // all reads of qs/ks/vt done -> o overlay becomes legal

    // write attention output (split) into overlay
    #pragma unroll
    for (int mt = 0; mt < 4; ++mt)
        #pragma unroll
        for (int i = 0; i < 4; ++i) {
            int row = mt * 16 + g * 4 + i;
            float f = oacc[mt][i];
            bf16_t h = (bf16_t)f;
            o_hi[row * 96 + w * 16 + c] = h;
            o_lo[row * 96 + w * 16 + c] = (bf16_t)(f - (float)h);
        }
    __syncthreads();

    // ---- Phase 3: out-projection (split-bf16, 3-term). Wave w -> cols [w*16, w*16+16) ----
    f32x4 acc3[4];
    {
        float bo = b_out[w * 16 + c];
        #pragma unroll
        for (int mt = 0; mt < 4; ++mt) acc3[mt] = (f32x4){bo, bo, bo, bo};
    }
    #pragma unroll
    for (int ks = 0; ks < 3; ++ks) {
        bf16x8 ah[4], al[4];
        #pragma unroll
        for (int mt = 0; mt < 4; ++mt) {
            ah[mt] = *(const bf16x8*)&o_hi[(mt * 16 + c) * 96 + ks * 32 + g * 8];
            al[mt] = *(const bf16x8*)&o_lo[(mt * 16 + c) * 96 + ks * 32 + g * 8];
        }
        const bf16x8 bh = *(const bf16x8*)&wo_hi[((w * 3 + ks) * 64 + lane) * 8];
        const bf16x8 bl = *(const bf16x8*)&wo_lo[((w * 3 + ks) * 64 + lane) * 8];
        #pragma unroll
        for (int mt = 0; mt < 4; ++mt) {
            acc3[mt] = __builtin_amdgcn_mfma_f32_16x16x32_bf16(ah[mt], bh, acc3[mt], 0, 0, 0);
            acc3[mt] = __builtin_amdgcn_mfma_f32_16x16x32_bf16(ah[mt], bl, acc3[mt], 0, 0, 0);
            acc3[mt] = __builtin_amdgcn_mfma_f32_16x16x32_bf16(al[mt], bh, acc3[mt], 0, 0, 0);
        }
    }
    // store (shifted scatter)
    #pragma unroll
    for (int mt = 0; mt < 4; ++mt)
        #pragma unroll
        for (int i = 0; i < 4; ++i) {
            int row = mt * 16 + g * 4 + i;
            int r = row >> 3, cl = row & 7;
            int gh = (wi * WSZ + r + 4) & 255;
            int gw = (wj * WSZ + cl + 4) & 255;
            out[(((size_t)b * HH + gh) * HH + gw) * DD + w * 16 + c] = acc3[mt][i];
        }
}

extern "C" void kernel_launch(void* const* d_in, const int* in_sizes, int n_in,
                              void* d_out, int out_size, void* d_ws, size_t ws_size,
                              hipStream_t stream) {
    const float* x    = (const float*)d_in[0];
    const float* wqkv = (const float*)d_in[1];
    const float* bqkv = (const float*)d_in[2];
    const float* wout = (const float*)d_in[3];
    const float* bout = (const float*)d_in[4];
    const float* rpe  = (const float*)d_in[5];
    float* out = (float*)d_out;
    char* ws = (char*)d_ws;

    const int B = in_sizes[0] / (HH * HH * DD);

    hipLaunchKernelGGL(prep_kernel, dim3(108), dim3(256), 0, stream, wqkv, wout, rpe, ws);
    hipLaunchKernelGGL(swin_mfma, dim3(B * 1024), dim3(384), LDS_BYTES, stream,
                       x, bqkv, bout, (const char*)ws, out);
}

// Round 6
// 264.175 us; speedup vs baseline: 2.1206x; 1.1461x over previous
//
#include <hip/hip_runtime.h>
#include <stdint.h>

#define HH    256
#define DD    96
#define NH    6
#define WSZ   8

typedef __bf16 bf16_t;
typedef bf16_t bf16x8 __attribute__((ext_vector_type(8)));
typedef float  f32x4  __attribute__((ext_vector_type(4)));

union U4 { bf16x8 v; uint32_t u[4]; };
union U2 { bf16_t h[2]; uint32_t u; };

static __device__ __forceinline__ uint32_t pack2(float a, float b) {
    U2 x; x.h[0] = (bf16_t)a; x.h[1] = (bf16_t)b; return x.u;
}

// ---- workspace layout (bytes) ----
#define OFF_WQT_HI 0        // Q,K transposed A-frags: 36 frags * 512 el = 36864 B
#define OFF_WQT_LO 36864
#define OFF_WV_HI  73728    // V B-frags: 18 frags * 512 el = 18432 B
#define OFF_WV_LO  92160
#define OFF_WO_HI  110592   // out-proj B-frags: 18 frags
#define OFF_WO_LO  129024
#define OFF_RPE    147456   // 6*64*64 f32 = 98304 B, layout [h][q][k]
// total 245760 B

// ---- LDS overlay arena (bytes): 38400 -> 4 blocks/CU ----
// phase 0/1: xs_hi [64][128]swz @0 (16384) | xs_lo @16384 (16384)
// phase 2  : qs [64][16] @0 (12288 for 6 heads) | ks @12288 | vt [6][16][72] @24576 (13824)
// phase 3  : o_hi [64][128]swz @0 | o_lo @16384
#define LDS_BYTES 38400

// swizzled element index into a [64][128] bf16 buffer (16B-chunk XOR)
static __device__ __forceinline__ int swz(int row, int col) {
    return row * 128 + ((((col >> 3) ^ (row & 15)) & 15) << 3) + (col & 7);
}

__global__ __launch_bounds__(256)
void prep_kernel(const float* __restrict__ wqkv, const float* __restrict__ wout,
                 const float* __restrict__ rpe, char* __restrict__ ws)
{
    bf16_t* wqt_hi = (bf16_t*)(ws + OFF_WQT_HI);
    bf16_t* wqt_lo = (bf16_t*)(ws + OFF_WQT_LO);
    bf16_t* wv_hi  = (bf16_t*)(ws + OFF_WV_HI);
    bf16_t* wv_lo  = (bf16_t*)(ws + OFF_WV_LO);
    bf16_t* wo_hi  = (bf16_t*)(ws + OFF_WO_HI);
    bf16_t* wo_lo  = (bf16_t*)(ws + OFF_WO_LO);
    float*  rpe_b  = (float*)(ws + OFF_RPE);

    int idx = blockIdx.x * 256 + threadIdx.x;
    int j = idx & 7, lane = (idx >> 3) & 63, frag = idx >> 9;
    int c = lane & 15, g = lane >> 4;

    // Q,K transposed A-frags: lane(c,g) holds W^T[head-dim c][k=ks*32+g*8+j]
    if (idx < 18432) {
        int ks = frag % 3, r2 = frag / 3, wh = r2 % 6, t = r2 / 6;  // t: 0=Q,1=K
        int k = ks * 32 + g * 8 + j;
        float v = wqkv[k * 288 + t * 96 + wh * 16 + c];
        bf16_t h = (bf16_t)v;
        wqt_hi[idx] = h;
        wqt_lo[idx] = (bf16_t)(v - (float)h);
    }
    // V B-frags: lane(c,g) holds Wv[k=ks*32+g*8+j][n=wh*16+c]
    if (idx < 9216) {
        int ks = frag % 3, wh = frag / 3;
        int k = ks * 32 + g * 8 + j;
        float v = wqkv[k * 288 + 192 + wh * 16 + c];
        bf16_t h = (bf16_t)v;
        wv_hi[idx] = h;
        wv_lo[idx] = (bf16_t)(v - (float)h);
        // out-proj B-frags (same shape)
        float v2 = wout[k * 96 + wh * 16 + c];
        bf16_t h2 = (bf16_t)v2;
        wo_hi[idx] = h2;
        wo_lo[idx] = (bf16_t)(v2 - (float)h2);
    }
    // expanded rpe bias: [h][q][k]
    if (idx < 24576) {
        int h = idx >> 12, r = idx & 4095, q = r >> 6, k = r & 63;
        int qr = q >> 3, qc = q & 7, kr = k >> 3, kc = k & 7;
        rpe_b[idx] = rpe[((qr - kr + 7) * 15 + (qc - kc + 7)) * NH + h];
    }
}

__global__ __launch_bounds__(384, 4)
void swin_mfma(const float* __restrict__ x,
               const float* __restrict__ b_qkv,
               const float* __restrict__ b_out,
               const char*  __restrict__ ws,
               float* __restrict__ out)
{
    extern __shared__ char smem[];
    bf16_t* xs_hi = (bf16_t*)(smem);            // phase 0/1 (swizzled [64][128])
    bf16_t* xs_lo = (bf16_t*)(smem + 16384);
    bf16_t* qs    = (bf16_t*)(smem);            // phase 2 overlay: [6][64][16]
    bf16_t* ks_l  = (bf16_t*)(smem + 12288);
    bf16_t* vt    = (bf16_t*)(smem + 24576);    // [6][16][72]
    bf16_t* o_hi  = (bf16_t*)(smem);            // phase 3 overlay (swizzled [64][128])
    bf16_t* o_lo  = (bf16_t*)(smem + 16384);

    const bf16_t* wqt_hi = (const bf16_t*)(ws + OFF_WQT_HI);
    const bf16_t* wqt_lo = (const bf16_t*)(ws + OFF_WQT_LO);
    const bf16_t* wv_hi  = (const bf16_t*)(ws + OFF_WV_HI);
    const bf16_t* wv_lo  = (const bf16_t*)(ws + OFF_WV_LO);
    const bf16_t* wo_hi  = (const bf16_t*)(ws + OFF_WO_HI);
    const bf16_t* wo_lo  = (const bf16_t*)(ws + OFF_WO_LO);
    const float*  rpe_b  = (const float*)(ws + OFF_RPE);

    const int blk = blockIdx.x;
    const int b   = blk >> 10;
    const int wi  = (blk >> 5) & 31;
    const int wj  = blk & 31;

    const int tid  = threadIdx.x;
    const int lane = tid & 63;
    const int w    = tid >> 6;      // wave = head
    const int g    = lane >> 4;     // lane group 0..3
    const int c    = lane & 15;

    const f32x4 zf = {0.f, 0.f, 0.f, 0.f};

    // ---- Phase 0: stage x -> swizzled xs_hi/xs_lo (shifted gather) ----
    #pragma unroll
    for (int it = 0; it < 4; ++it) {
        int f4  = tid + it * 384;          // float4 index over [64][24]
        int row = f4 / 24, c4 = f4 - row * 24;
        int r = row >> 3, cl = row & 7;
        int gh = (wi * WSZ + r + 4) & 255;
        int gw = (wj * WSZ + cl + 4) & 255;
        const float4 v = *(const float4*)(x + (((size_t)b * HH + gh) * HH + gw) * DD + c4 * 4);
        float f0 = v.x, f1 = v.y, f2 = v.z, f3 = v.w;
        bf16_t h0 = (bf16_t)f0, h1 = (bf16_t)f1, h2 = (bf16_t)f2, h3 = (bf16_t)f3;
        uint2 hv, lv;
        hv.x = pack2(f0, f1); hv.y = pack2(f2, f3);
        lv.x = pack2(f0 - (float)h0, f1 - (float)h1);
        lv.y = pack2(f2 - (float)h2, f3 - (float)h3);
        int e = swz(row, c4 * 4);
        *(uint2*)&xs_hi[e] = hv;
        *(uint2*)&xs_lo[e] = lv;
    }
    __syncthreads();

    // ---- Phase 1: QKV projection (split-bf16, 3-term) ----
    // Q,K transposed: C = W^T x^T -> lane(c,g) holds {Q,K}^T[dk=4g+i][pos=pt*16+c]
    // V normal: lane(c,g) holds V[pos=mt*16+4g+i][dk=c]
    f32x4 aq[4], akk[4], av[4];
    {
        const float4 bq4 = *(const float4*)&b_qkv[w * 16 + 4 * g];
        const float4 bk4 = *(const float4*)&b_qkv[96 + w * 16 + 4 * g];
        const float  bv  = b_qkv[192 + w * 16 + c];
        #pragma unroll
        for (int t4 = 0; t4 < 4; ++t4) {
            aq[t4]  = (f32x4){bq4.x, bq4.y, bq4.z, bq4.w};
            akk[t4] = (f32x4){bk4.x, bk4.y, bk4.z, bk4.w};
            av[t4]  = (f32x4){bv, bv, bv, bv};
        }
    }
    #pragma unroll
    for (int ks = 0; ks < 3; ++ks) {
        bf16x8 ah[4], al[4];
        #pragma unroll
        for (int mt = 0; mt < 4; ++mt) {
            int e = (mt * 16 + c) * 128 + (((ks * 4 + g) ^ c) << 3);
            ah[mt] = *(const bf16x8*)&xs_hi[e];
            al[mt] = *(const bf16x8*)&xs_lo[e];
        }
        const bf16x8 qh = *(const bf16x8*)&wqt_hi[((0 * 6 + w) * 3 + ks) * 512 + lane * 8];
        const bf16x8 ql = *(const bf16x8*)&wqt_lo[((0 * 6 + w) * 3 + ks) * 512 + lane * 8];
        const bf16x8 kh = *(const bf16x8*)&wqt_hi[((6 + w) * 3 + ks) * 512 + lane * 8];
        const bf16x8 kl = *(const bf16x8*)&wqt_lo[((6 + w) * 3 + ks) * 512 + lane * 8];
        const bf16x8 vh = *(const bf16x8*)&wv_hi[(w * 3 + ks) * 512 + lane * 8];
        const bf16x8 vl = *(const bf16x8*)&wv_lo[(w * 3 + ks) * 512 + lane * 8];
        #pragma unroll
        for (int mt = 0; mt < 4; ++mt) {
            aq[mt] = __builtin_amdgcn_mfma_f32_16x16x32_bf16(qh, ah[mt], aq[mt], 0, 0, 0);
            aq[mt] = __builtin_amdgcn_mfma_f32_16x16x32_bf16(ql, ah[mt], aq[mt], 0, 0, 0);
            aq[mt] = __builtin_amdgcn_mfma_f32_16x16x32_bf16(qh, al[mt], aq[mt], 0, 0, 0);
            akk[mt] = __builtin_amdgcn_mfma_f32_16x16x32_bf16(kh, ah[mt], akk[mt], 0, 0, 0);
            akk[mt] = __builtin_amdgcn_mfma_f32_16x16x32_bf16(kl, ah[mt], akk[mt], 0, 0, 0);
            akk[mt] = __builtin_amdgcn_mfma_f32_16x16x32_bf16(kh, al[mt], akk[mt], 0, 0, 0);
            av[mt] = __builtin_amdgcn_mfma_f32_16x16x32_bf16(ah[mt], vh, av[mt], 0, 0, 0);
            av[mt] = __builtin_amdgcn_mfma_f32_16x16x32_bf16(ah[mt], vl, av[mt], 0, 0, 0);
            av[mt] = __builtin_amdgcn_mfma_f32_16x16x32_bf16(al[mt], vh, av[mt], 0, 0, 0);
        }
    }
    __syncthreads();   // all proj reads of xs done -> overlay becomes legal

    // write Q (x0.25), K: [pos][dk], dk-consecutive b64 writes; V^T: [dk][pos]
    #pragma unroll
    for (int pt = 0; pt < 4; ++pt) {
        uint2 uq, uk, uv;
        uq.x = pack2(aq[pt][0] * 0.25f, aq[pt][1] * 0.25f);
        uq.y = pack2(aq[pt][2] * 0.25f, aq[pt][3] * 0.25f);
        uk.x = pack2(akk[pt][0], akk[pt][1]);
        uk.y = pack2(akk[pt][2], akk[pt][3]);
        uv.x = pack2(av[pt][0], av[pt][1]);
        uv.y = pack2(av[pt][2], av[pt][3]);
        *(uint2*)&qs[w * 1024 + (pt * 16 + c) * 16 + 4 * g] = uq;
        *(uint2*)&ks_l[w * 1024 + (pt * 16 + c) * 16 + 4 * g] = uk;
        *(uint2*)&vt[w * 1152 + c * 72 + pt * 16 + 4 * g] = uv;
    }
    // no barrier: attention reads only this wave's own head data (lgkmcnt handles it)

    // ---- Phase 2: attention for head w (S^T = K @ Q^T, K-dim 16 zero-padded to 32) ----
    U4 z4; z4.u[0] = z4.u[1] = z4.u[2] = z4.u[3] = 0;
    bf16x8 ak[4], bq[4];
    #pragma unroll
    for (int kt = 0; kt < 4; ++kt) {
        U4 t = z4;
        if (g < 2) t.v = *(const bf16x8*)&ks_l[w * 1024 + (kt * 16 + c) * 16 + g * 8];
        ak[kt] = t.v;
    }
    #pragma unroll
    for (int nt = 0; nt < 4; ++nt) {
        U4 t = z4;
        if (g < 2) t.v = *(const bf16x8*)&qs[w * 1024 + (nt * 16 + c) * 16 + g * 8];
        bq[nt] = t.v;
    }
    f32x4 st[4][4];
    #pragma unroll
    for (int kt = 0; kt < 4; ++kt)
        #pragma unroll
        for (int nt = 0; nt < 4; ++nt)
            st[kt][nt] = __builtin_amdgcn_mfma_f32_16x16x32_bf16(ak[kt], bq[nt], zf, 0, 0, 0);

    // rpe + mask + softmax (per lane: 4 q's x 16 k's; row-reduce over 4 lanes)
    const float* rpe_w = rpe_b + w * 4096;
    const int e_wi = (wi == 31), e_wj = (wj == 31);
    const bool edge = e_wi || e_wj;
    int rk[4][4];
    #pragma unroll
    for (int kt = 0; kt < 4; ++kt)
        #pragma unroll
        for (int i = 0; i < 4; ++i) {
            int k = kt * 16 + g * 4 + i;
            int kr = k >> 3, kc = k & 7;
            rk[kt][i] = (e_wi ? (kr >= 4 ? 2 : 1) : 0) * 3 + (e_wj ? (kc >= 4 ? 2 : 1) : 0);
        }

    uint32_t pk[4][4][2];
    #pragma unroll
    for (int nt = 0; nt < 4; ++nt) {
        int q = nt * 16 + c, qr = q >> 3, qc = q & 7;
        int rq = (e_wi ? (qr >= 4 ? 2 : 1) : 0) * 3 + (e_wj ? (qc >= 4 ? 2 : 1) : 0);
        float sv[16];
        float m = -3.0e38f;
        #pragma unroll
        for (int kt = 0; kt < 4; ++kt) {
            const float4 rv = *(const float4*)&rpe_w[q * 64 + kt * 16 + g * 4];
            #pragma unroll
            for (int i = 0; i < 4; ++i) {
                float s = st[kt][nt][i] + ((const float*)&rv)[i];
                if (edge && (rk[kt][i] != rq)) s = -1e9f;
                sv[kt * 4 + i] = s;
                m = fmaxf(m, s);
            }
        }
        m = fmaxf(m, __shfl_xor(m, 16));
        m = fmaxf(m, __shfl_xor(m, 32));
        float sum = 0.f;
        #pragma unroll
        for (int e = 0; e < 16; ++e) { sv[e] = __expf(sv[e] - m); sum += sv[e]; }
        sum += __shfl_xor(sum, 16);
        sum += __shfl_xor(sum, 32);
        float rinv = 1.0f / sum;
        #pragma unroll
        for (int kt = 0; kt < 4; ++kt) {
            pk[nt][kt][0] = pack2(sv[kt * 4 + 0] * rinv, sv[kt * 4 + 1] * rinv);
            pk[nt][kt][1] = pack2(sv[kt * 4 + 2] * rinv, sv[kt * 4 + 3] * rinv);
        }
    }

    // PV transposed: O^T = V^T @ P^T -> lane(c,g) holds O^T[dk=4g+i][q=qt*16+c]
    f32x4 oacc[4];
    #pragma unroll
    for (int qt = 0; qt < 4; ++qt) oacc[qt] = zf;
    #pragma unroll
    for (int ks2 = 0; ks2 < 2; ++ks2) {
        const bf16x8 vv = *(const bf16x8*)&vt[w * 1152 + c * 72 + ks2 * 32 + g * 8];
        #pragma unroll
        for (int qt = 0; qt < 4; ++qt) {
            U4 af;
            #pragma unroll
            for (int jj = 0; jj < 4; ++jj) {
                int srcg = ((g & 1) << 1) + (jj >> 1);
                int src  = (srcg << 4) + c;
                uint32_t v0 = (uint32_t)__shfl((int)pk[qt][ks2 * 2 + 0][jj & 1], src);
                uint32_t v1 = (uint32_t)__shfl((int)pk[qt][ks2 * 2 + 1][jj & 1], src);
                af.u[jj] = (g >= 2) ? v1 : v0;
            }
            oacc[qt] = __builtin_amdgcn_mfma_f32_16x16x32_bf16(vv, af.v, oacc[qt], 0, 0, 0);
        }
    }
    __syncthreads();   // all reads of qs/ks/vt done -> o overlay becomes legal

    // write O^T (split) into swizzled o buffers: col = w*16+4g+i consecutive
    #pragma unroll
    for (int qt = 0; qt < 4; ++qt) {
        int row = qt * 16 + c;
        int colb = w * 16 + 4 * g;
        float f0 = oacc[qt][0], f1 = oacc[qt][1], f2 = oacc[qt][2], f3 = oacc[qt][3];
        bf16_t h0 = (bf16_t)f0, h1 = (bf16_t)f1, h2 = (bf16_t)f2, h3 = (bf16_t)f3;
        uint2 hv, lv;
        hv.x = pack2(f0, f1); hv.y = pack2(f2, f3);
        lv.x = pack2(f0 - (float)h0, f1 - (float)h1);
        lv.y = pack2(f2 - (float)h2, f3 - (float)h3);
        int e = swz(row, colb);
        *(uint2*)&o_hi[e] = hv;
        *(uint2*)&o_lo[e] = lv;
    }
    __syncthreads();

    // ---- Phase 3: out-projection (split-bf16, 3-term). Wave w -> cols [w*16, w*16+16) ----
    f32x4 acc3[4];
    {
        float bo = b_out[w * 16 + c];
        #pragma unroll
        for (int mt = 0; mt < 4; ++mt) acc3[mt] = (f32x4){bo, bo, bo, bo};
    }
    #pragma unroll
    for (int ks = 0; ks < 3; ++ks) {
        bf16x8 ah[4], al[4];
        #pragma unroll
        for (int mt = 0; mt < 4; ++mt) {
            int e = (mt * 16 + c) * 128 + (((ks * 4 + g) ^ c) << 3);
            ah[mt] = *(const bf16x8*)&o_hi[e];
            al[mt] = *(const bf16x8*)&o_lo[e];
        }
        const bf16x8 bh = *(const bf16x8*)&wo_hi[(w * 3 + ks) * 512 + lane * 8];
        const bf16x8 bl = *(const bf16x8*)&wo_lo[(w * 3 + ks) * 512 + lane * 8];
        #pragma unroll
        for (int mt = 0; mt < 4; ++mt) {
            acc3[mt] = __builtin_amdgcn_mfma_f32_16x16x32_bf16(ah[mt], bh, acc3[mt], 0, 0, 0);
            acc3[mt] = __builtin_amdgcn_mfma_f32_16x16x32_bf16(ah[mt], bl, acc3[mt], 0, 0, 0);
            acc3[mt] = __builtin_amdgcn_mfma_f32_16x16x32_bf16(al[mt], bh, acc3[mt], 0, 0, 0);
        }
    }
    // store (shifted scatter)
    #pragma unroll
    for (int mt = 0; mt < 4; ++mt)
        #pragma unroll
        for (int i = 0; i < 4; ++i) {
            int row = mt * 16 + g * 4 + i;
            int r = row >> 3, cl = row & 7;
            int gh = (wi * WSZ + r + 4) & 255;
            int gw = (wj * WSZ + cl + 4) & 255;
            out[(((size_t)b * HH + gh) * HH + gw) * DD + w * 16 + c] = acc3[mt][i];
        }
}

extern "C" void kernel_launch(void* const* d_in, const int* in_sizes, int n_in,
                              void* d_out, int out_size, void* d_ws, size_t ws_size,
                              hipStream_t stream) {
    const float* x    = (const float*)d_in[0];
    const float* wqkv = (const float*)d_in[1];
    const float* bqkv = (const float*)d_in[2];
    const float* wout = (const float*)d_in[3];
    const float* bout = (const float*)d_in[4];
    const float* rpe  = (const float*)d_in[5];
    float* out = (float*)d_out;
    char* ws = (char*)d_ws;

    const int B = in_sizes[0] / (HH * HH * DD);

    hipLaunchKernelGGL(prep_kernel, dim3(96), dim3(256), 0, stream, wqkv, wout, rpe, ws);
    hipLaunchKernelGGL(swin_mfma, dim3(B * 1024), dim3(384), LDS_BYTES, stream,
                       x, bqkv, bout, (const char*)ws, out);
}

// Round 7
// 262.473 us; speedup vs baseline: 2.1344x; 1.0065x over previous
//
#include <hip/hip_runtime.h>
#include <stdint.h>

#define HH    256
#define DD    96
#define NH    6
#define WSZ   8

typedef __bf16 bf16_t;
typedef bf16_t bf16x8 __attribute__((ext_vector_type(8)));
typedef short  s16x4  __attribute__((ext_vector_type(4)));
typedef float  f32x4  __attribute__((ext_vector_type(4)));

union U2  { bf16_t h[2]; uint32_t u; };
union Upk { uint32_t u[2]; s16x4 s; };

static __device__ __forceinline__ uint32_t pack2(float a, float b) {
    U2 x; x.h[0] = (bf16_t)a; x.h[1] = (bf16_t)b; return x.u;
}

static __device__ __forceinline__ f32x4 mfma16(s16x4 a, s16x4 b, f32x4 c) {
#if __has_builtin(__builtin_amdgcn_mfma_f32_16x16x16bf16_1k)
    return __builtin_amdgcn_mfma_f32_16x16x16bf16_1k(a, b, c, 0, 0, 0);
#else
    f32x4 d;
    asm volatile("v_mfma_f32_16x16x16_bf16 %0, %1, %2, %3"
                 : "=v"(d) : "v"(a), "v"(b), "v"(c));
    return d;
#endif
}

// ---- workspace layout (bytes) ----
#define OFF_WQT_HI 0        // Q,K transposed A-frags: 36 frags * 512 el = 36864 B
#define OFF_WQT_LO 36864
#define OFF_WV_HI  73728    // V B-frags: 18 frags * 512 el = 18432 B
#define OFF_WV_LO  92160
#define OFF_WO_HI  110592   // out-proj B-frags: 18 frags
#define OFF_WO_LO  129024
#define OFF_RPE    147456   // 6*64*64 f32 = 98304 B, layout [h][q][k]
// total 245760 B

// ---- LDS overlay arena: 32768 B -> 5 blocks/CU (wave-capped) ----
// phase 0/1: xs_hi [64][128]swz @0 (16384) | xs_lo @16384 (16384)
// phase 2/3: o_hi  [64][128]swz @0         | o_lo  @16384
#define LDS_BYTES 32768

// swizzled element index into a [64][128] bf16 buffer (16B-chunk XOR)
static __device__ __forceinline__ int swz(int row, int col) {
    return row * 128 + ((((col >> 3) ^ (row & 15)) & 15) << 3) + (col & 7);
}

__global__ __launch_bounds__(256)
void prep_kernel(const float* __restrict__ wqkv, const float* __restrict__ wout,
                 const float* __restrict__ rpe, char* __restrict__ ws)
{
    bf16_t* wqt_hi = (bf16_t*)(ws + OFF_WQT_HI);
    bf16_t* wqt_lo = (bf16_t*)(ws + OFF_WQT_LO);
    bf16_t* wv_hi  = (bf16_t*)(ws + OFF_WV_HI);
    bf16_t* wv_lo  = (bf16_t*)(ws + OFF_WV_LO);
    bf16_t* wo_hi  = (bf16_t*)(ws + OFF_WO_HI);
    bf16_t* wo_lo  = (bf16_t*)(ws + OFF_WO_LO);
    float*  rpe_b  = (float*)(ws + OFF_RPE);

    int idx = blockIdx.x * 256 + threadIdx.x;
    int j = idx & 7, lane = (idx >> 3) & 63, frag = idx >> 9;
    int c = lane & 15, g = lane >> 4;

    // Q,K transposed A-frags: lane(c,g) holds W^T[head-dim c][k=ks*32+g*8+j]
    if (idx < 18432) {
        int ks = frag % 3, r2 = frag / 3, wh = r2 % 6, t = r2 / 6;  // t: 0=Q,1=K
        int k = ks * 32 + g * 8 + j;
        float v = wqkv[k * 288 + t * 96 + wh * 16 + c];
        bf16_t h = (bf16_t)v;
        wqt_hi[idx] = h;
        wqt_lo[idx] = (bf16_t)(v - (float)h);
    }
    // V B-frags: lane(c,g) holds Wv[k=ks*32+g*8+j][n=wh*16+c]
    if (idx < 9216) {
        int ks = frag % 3, wh = frag / 3;
        int k = ks * 32 + g * 8 + j;
        float v = wqkv[k * 288 + 192 + wh * 16 + c];
        bf16_t h = (bf16_t)v;
        wv_hi[idx] = h;
        wv_lo[idx] = (bf16_t)(v - (float)h);
        // out-proj B-frags (same shape)
        float v2 = wout[k * 96 + wh * 16 + c];
        bf16_t h2 = (bf16_t)v2;
        wo_hi[idx] = h2;
        wo_lo[idx] = (bf16_t)(v2 - (float)h2);
    }
    // expanded rpe bias: [h][q][k]
    if (idx < 24576) {
        int h = idx >> 12, r = idx & 4095, q = r >> 6, k = r & 63;
        int qr = q >> 3, qc = q & 7, kr = k >> 3, kc = k & 7;
        rpe_b[idx] = rpe[((qr - kr + 7) * 15 + (qc - kc + 7)) * NH + h];
    }
}

__global__ __launch_bounds__(384, 4)
void swin_mfma(const float* __restrict__ x,
               const float* __restrict__ b_qkv,
               const float* __restrict__ b_out,
               const char*  __restrict__ ws,
               float* __restrict__ out)
{
    extern __shared__ char smem[];
    bf16_t* xs_hi = (bf16_t*)(smem);            // phase 0/1 (swizzled [64][128])
    bf16_t* xs_lo = (bf16_t*)(smem + 16384);
    bf16_t* o_hi  = (bf16_t*)(smem);            // phase 2/3 overlay
    bf16_t* o_lo  = (bf16_t*)(smem + 16384);

    const bf16_t* wqt_hi = (const bf16_t*)(ws + OFF_WQT_HI);
    const bf16_t* wqt_lo = (const bf16_t*)(ws + OFF_WQT_LO);
    const bf16_t* wv_hi  = (const bf16_t*)(ws + OFF_WV_HI);
    const bf16_t* wv_lo  = (const bf16_t*)(ws + OFF_WV_LO);
    const bf16_t* wo_hi  = (const bf16_t*)(ws + OFF_WO_HI);
    const bf16_t* wo_lo  = (const bf16_t*)(ws + OFF_WO_LO);
    const float*  rpe_b  = (const float*)(ws + OFF_RPE);

    const int blk = blockIdx.x;
    const int b   = blk >> 10;
    const int wi  = (blk >> 5) & 31;
    const int wj  = blk & 31;

    const int tid  = threadIdx.x;
    const int lane = tid & 63;
    const int w    = tid >> 6;      // wave = head
    const int g    = lane >> 4;     // lane group 0..3
    const int c    = lane & 15;

    const f32x4 zf = {0.f, 0.f, 0.f, 0.f};

    // ---- Phase 0: stage x -> swizzled xs_hi/xs_lo (shifted gather) ----
    #pragma unroll
    for (int it = 0; it < 4; ++it) {
        int f4  = tid + it * 384;          // float4 index over [64][24]
        int row = f4 / 24, c4 = f4 - row * 24;
        int r = row >> 3, cl = row & 7;
        int gh = (wi * WSZ + r + 4) & 255;
        int gw = (wj * WSZ + cl + 4) & 255;
        const float4 v = *(const float4*)(x + (((size_t)b * HH + gh) * HH + gw) * DD + c4 * 4);
        float f0 = v.x, f1 = v.y, f2 = v.z, f3 = v.w;
        bf16_t h0 = (bf16_t)f0, h1 = (bf16_t)f1, h2 = (bf16_t)f2, h3 = (bf16_t)f3;
        uint2 hv, lv;
        hv.x = pack2(f0, f1); hv.y = pack2(f2, f3);
        lv.x = pack2(f0 - (float)h0, f1 - (float)h1);
        lv.y = pack2(f2 - (float)h2, f3 - (float)h3);
        int e = swz(row, c4 * 4);
        *(uint2*)&xs_hi[e] = hv;
        *(uint2*)&xs_lo[e] = lv;
    }
    __syncthreads();

    // ---- Phase 1: QKV projection (split-bf16, 3-term) ----
    // Q,K transposed: lane(c,g) holds {Q,K}^T[dk=4g+i][pos=pt*16+c]
    // V normal:       lane(c,g) holds V[pos=pt*16+4g+i][dk=c]
    f32x4 aq[4], akk[4], av[4];
    {
        const float4 bq4 = *(const float4*)&b_qkv[w * 16 + 4 * g];
        const float4 bk4 = *(const float4*)&b_qkv[96 + w * 16 + 4 * g];
        const float  bv  = b_qkv[192 + w * 16 + c];
        #pragma unroll
        for (int t4 = 0; t4 < 4; ++t4) {
            aq[t4]  = (f32x4){bq4.x, bq4.y, bq4.z, bq4.w};
            akk[t4] = (f32x4){bk4.x, bk4.y, bk4.z, bk4.w};
            av[t4]  = (f32x4){bv, bv, bv, bv};
        }
    }
    #pragma unroll
    for (int ks = 0; ks < 3; ++ks) {
        bf16x8 ah[4], al[4];
        #pragma unroll
        for (int mt = 0; mt < 4; ++mt) {
            int e = (mt * 16 + c) * 128 + (((ks * 4 + g) ^ c) << 3);
            ah[mt] = *(const bf16x8*)&xs_hi[e];
            al[mt] = *(const bf16x8*)&xs_lo[e];
        }
        const bf16x8 qh = *(const bf16x8*)&wqt_hi[(w * 3 + ks) * 512 + lane * 8];
        const bf16x8 ql = *(const bf16x8*)&wqt_lo[(w * 3 + ks) * 512 + lane * 8];
        const bf16x8 kh = *(const bf16x8*)&wqt_hi[((6 + w) * 3 + ks) * 512 + lane * 8];
        const bf16x8 kl = *(const bf16x8*)&wqt_lo[((6 + w) * 3 + ks) * 512 + lane * 8];
        const bf16x8 vh = *(const bf16x8*)&wv_hi[(w * 3 + ks) * 512 + lane * 8];
        const bf16x8 vl = *(const bf16x8*)&wv_lo[(w * 3 + ks) * 512 + lane * 8];
        #pragma unroll
        for (int mt = 0; mt < 4; ++mt) {
            aq[mt] = __builtin_amdgcn_mfma_f32_16x16x32_bf16(qh, ah[mt], aq[mt], 0, 0, 0);
            aq[mt] = __builtin_amdgcn_mfma_f32_16x16x32_bf16(ql, ah[mt], aq[mt], 0, 0, 0);
            aq[mt] = __builtin_amdgcn_mfma_f32_16x16x32_bf16(qh, al[mt], aq[mt], 0, 0, 0);
            akk[mt] = __builtin_amdgcn_mfma_f32_16x16x32_bf16(kh, ah[mt], akk[mt], 0, 0, 0);
            akk[mt] = __builtin_amdgcn_mfma_f32_16x16x32_bf16(kl, ah[mt], akk[mt], 0, 0, 0);
            akk[mt] = __builtin_amdgcn_mfma_f32_16x16x32_bf16(kh, al[mt], akk[mt], 0, 0, 0);
            av[mt] = __builtin_amdgcn_mfma_f32_16x16x32_bf16(ah[mt], vh, av[mt], 0, 0, 0);
            av[mt] = __builtin_amdgcn_mfma_f32_16x16x32_bf16(ah[mt], vl, av[mt], 0, 0, 0);
            av[mt] = __builtin_amdgcn_mfma_f32_16x16x32_bf16(al[mt], vh, av[mt], 0, 0, 0);
        }
    }
    __syncthreads();   // all proj reads of xs done -> o overlay becomes legal

    // convert proj outputs to 16x16x16 MFMA fragments (all lane-local!)
    s16x4 aqb[4], akb[4], avb[4];
    #pragma unroll
    for (int t = 0; t < 4; ++t) {
        Upk uq, uk, uv;
        uq.u[0] = pack2(aq[t][0] * 0.25f, aq[t][1] * 0.25f);   // fold 1/sqrt(dk)
        uq.u[1] = pack2(aq[t][2] * 0.25f, aq[t][3] * 0.25f);
        uk.u[0] = pack2(akk[t][0], akk[t][1]);
        uk.u[1] = pack2(akk[t][2], akk[t][3]);
        uv.u[0] = pack2(av[t][0], av[t][1]);
        uv.u[1] = pack2(av[t][2], av[t][3]);
        aqb[t] = uq.s; akb[t] = uk.s; avb[t] = uv.s;
    }

    // ---- Phase 2: attention, fully in registers ----
    const float* rpe_w = rpe_b + w * 4096;
    const int e_wi = (wi == 31), e_wj = (wj == 31);
    const bool edge = e_wi || e_wj;
    int rk[4][4];
    #pragma unroll
    for (int kt = 0; kt < 4; ++kt)
        #pragma unroll
        for (int i = 0; i < 4; ++i) {
            int k = kt * 16 + g * 4 + i;
            int kr = k >> 3, kc = k & 7;
            rk[kt][i] = (e_wi ? (kr >= 4 ? 2 : 1) : 0) * 3 + (e_wj ? (kc >= 4 ? 2 : 1) : 0);
        }

    #pragma unroll
    for (int nt = 0; nt < 4; ++nt) {
        // S^T column tile: st[kt] holds S^T[k=kt*16+4g+i][q=nt*16+c]
        f32x4 stc[4];
        #pragma unroll
        for (int kt = 0; kt < 4; ++kt)
            stc[kt] = mfma16(akb[kt], aqb[nt], zf);

        int q = nt * 16 + c, qr = q >> 3, qc = q & 7;
        int rq = (e_wi ? (qr >= 4 ? 2 : 1) : 0) * 3 + (e_wj ? (qc >= 4 ? 2 : 1) : 0);
        float sv[16];
        float m = -3.0e38f;
        #pragma unroll
        for (int kt = 0; kt < 4; ++kt) {
            const float4 rv = *(const float4*)&rpe_w[q * 64 + kt * 16 + g * 4];
            #pragma unroll
            for (int i = 0; i < 4; ++i) {
                float s = stc[kt][i] + ((const float*)&rv)[i];
                if (edge && (rk[kt][i] != rq)) s = -1e9f;
                sv[kt * 4 + i] = s;
                m = fmaxf(m, s);
            }
        }
        m = fmaxf(m, __shfl_xor(m, 16));
        m = fmaxf(m, __shfl_xor(m, 32));
        float sum = 0.f;
        #pragma unroll
        for (int e = 0; e < 16; ++e) { sv[e] = __expf(sv[e] - m); sum += sv[e]; }
        sum += __shfl_xor(sum, 16);
        sum += __shfl_xor(sum, 32);
        float rinv = 1.0f / sum;

        // PV: O^T tile = sum_ks V^T-frag x P^T-frag  (both lane-local)
        f32x4 oa = zf;
        #pragma unroll
        for (int ks2 = 0; ks2 < 4; ++ks2) {
            Upk pb;
            pb.u[0] = pack2(sv[ks2 * 4 + 0] * rinv, sv[ks2 * 4 + 1] * rinv);
            pb.u[1] = pack2(sv[ks2 * 4 + 2] * rinv, sv[ks2 * 4 + 3] * rinv);
            oa = mfma16(avb[ks2], pb.s, oa);
        }
        // write O (split) into swizzled o buffers: row=q, cols w*16+4g..+3
        {
            int row = nt * 16 + c;
            int colb = w * 16 + 4 * g;
            float f0 = oa[0], f1 = oa[1], f2 = oa[2], f3 = oa[3];
            bf16_t h0 = (bf16_t)f0, h1 = (bf16_t)f1, h2 = (bf16_t)f2, h3 = (bf16_t)f3;
            uint2 hv, lv;
            hv.x = pack2(f0, f1); hv.y = pack2(f2, f3);
            lv.x = pack2(f0 - (float)h0, f1 - (float)h1);
            lv.y = pack2(f2 - (float)h2, f3 - (float)h3);
            int e = swz(row, colb);
            *(uint2*)&o_hi[e] = hv;
            *(uint2*)&o_lo[e] = lv;
        }
    }
    __syncthreads();

    // ---- Phase 3: out-projection (split-bf16, 3-term). Wave w -> cols [w*16, w*16+16) ----
    f32x4 acc3[4];
    {
        const float4 bo4 = *(const float4*)&b_out[w * 16 + 4 * g];
        #pragma unroll
        for (int mt = 0; mt < 4; ++mt) acc3[mt] = (f32x4){0.f, 0.f, 0.f, 0.f};
        // note: bias added per-element at store (C layout col=c? no: col=w*16+4g+i)
        #pragma unroll
        for (int mt = 0; mt < 4; ++mt) {
            acc3[mt][0] = bo4.x; acc3[mt][1] = bo4.y;
            acc3[mt][2] = bo4.z; acc3[mt][3] = bo4.w;
        }
    }
    #pragma unroll
    for (int ks = 0; ks < 3; ++ks) {
        bf16x8 ah[4], al[4];
        #pragma unroll
        for (int mt = 0; mt < 4; ++mt) {
            int e = (mt * 16 + c) * 128 + (((ks * 4 + g) ^ c) << 3);
            ah[mt] = *(const bf16x8*)&o_hi[e];
            al[mt] = *(const bf16x8*)&o_lo[e];
        }
        const bf16x8 bh = *(const bf16x8*)&wo_hi[(w * 3 + ks) * 512 + lane * 8];
        const bf16x8 bl = *(const bf16x8*)&wo_lo[(w * 3 + ks) * 512 + lane * 8];
        #pragma unroll
        for (int mt = 0; mt < 4; ++mt) {
            acc3[mt] = __builtin_amdgcn_mfma_f32_16x16x32_bf16(ah[mt], bh, acc3[mt], 0, 0, 0);
            acc3[mt] = __builtin_amdgcn_mfma_f32_16x16x32_bf16(ah[mt], bl, acc3[mt], 0, 0, 0);
            acc3[mt] = __builtin_amdgcn_mfma_f32_16x16x32_bf16(al[mt], bh, acc3[mt], 0, 0, 0);
        }
    }
    // wait: C layout for 16x16x32 with A=o-frag: col=lane&15? No — operands (ah, bh):
    // A=o rows (m), B=wo cols (n): C[row=mt*16+4g+i? ] -- same mapping as rounds 3-6:
    // lane(c,g) holds C[row=mt*16+c][col-group w*16+4g+i]? NO — verified mapping:
    // C col=lane&15 applies to B's n-index only when B-frag col=lane&15. wo frags have
    // n=wh*16+c, so C[row=mt*16+4g+i][col=w*16+c].  (identical to rounds 3-6 stores)
    // -> bias must be b_out[w*16+c], store scalar like round 6.  Fix below.
    {
        // correct bias: we initialized with bo4 (wrong axis) -> compensate:
        // acc3 currently = bo4[i] + true_gemm. Subtract bo4[i], add b_out[w*16+c].
        const float4 bo4 = *(const float4*)&b_out[w * 16 + 4 * g];
        const float boc = b_out[w * 16 + c];
        #pragma unroll
        for (int mt = 0; mt < 4; ++mt)
            #pragma unroll
            for (int i = 0; i < 4; ++i)
                acc3[mt][i] = acc3[mt][i] - ((const float*)&bo4)[i] + boc;
    }
    // store (shifted scatter): lane(c,g) holds out[row=mt*16+g*4+i][col=w*16+c]
    #pragma unroll
    for (int mt = 0; mt < 4; ++mt)
        #pragma unroll
        for (int i = 0; i < 4; ++i) {
            int row = mt * 16 + g * 4 + i;
            int r = row >> 3, cl = row & 7;
            int gh = (wi * WSZ + r + 4) & 255;
            int gw = (wj * WSZ + cl + 4) & 255;
            out[(((size_t)b * HH + gh) * HH + gw) * DD + w * 16 + c] = acc3[mt][i];
        }
}

extern "C" void kernel_launch(void* const* d_in, const int* in_sizes, int n_in,
                              void* d_out, int out_size, void* d_ws, size_t ws_size,
                              hipStream_t stream) {
    const float* x    = (const float*)d_in[0];
    const float* wqkv = (const float*)d_in[1];
    const float* bqkv = (const float*)d_in[2];
    const float* wout = (const float*)d_in[3];
    const float* bout = (const float*)d_in[4];
    const float* rpe  = (const float*)d_in[5];
    float* out = (float*)d_out;
    char* ws = (char*)d_ws;

    const int B = in_sizes[0] / (HH * HH * DD);

    hipLaunchKernelGGL(prep_kernel, dim3(96), dim3(256), 0, stream, wqkv, wout, rpe, ws);
    hipLaunchKernelGGL(swin_mfma, dim3(B * 1024), dim3(384), LDS_BYTES, stream,
                       x, bqkv, bout, (const char*)ws, out);
}